// Round 11
// baseline (259.221 us; speedup 1.0000x reference)
//
#include <hip/hip_runtime.h>

typedef __bf16 bf16x8 __attribute__((ext_vector_type(8)));
typedef float  f32x4  __attribute__((ext_vector_type(4)));

#define AS1 __attribute__((address_space(1)))
#define AS3 __attribute__((address_space(3)))

__device__ __forceinline__ float bf2f(ushort u) {
    union { unsigned int i; float f; } v; v.i = ((unsigned int)u) << 16; return v.f;
}
__device__ __forceinline__ ushort f2bf(float f) {
    union { float f; unsigned int i; } v; v.f = f;
    unsigned int i = v.i;
    unsigned int r = i + 0x7FFFu + ((i >> 16) & 1u);   // RNE
    return (ushort)(r >> 16);
}
__device__ __forceinline__ float bflo(unsigned int u) { return bf2f((ushort)(u & 0xFFFFu)); }
__device__ __forceinline__ float bfhi(unsigned int u) { return bf2f((ushort)(u >> 16)); }
__device__ __forceinline__ float gelu_f(float v) {
    return 0.5f * v * (1.f + erff(v * 0.70710678118654752f));
}

// wave-level inline dtype sniff: 1 = bf16 inputs, 0 = f32
__device__ __forceinline__ bool sniff_inline(const ushort* __restrict__ x) {
    const int lane = threadIdx.x & 63;
    int cnt = 0;
    #pragma unroll
    for (int r = 0; r < 4; r++) {
        const ushort u = x[lane + r * 64];
        const int e = (u >> 7) & 0xFF;
        if ((u & 0x7FFF) == 0 || (e >= 112 && e <= 141)) cnt++;
    }
    #pragma unroll
    for (int o = 32; o > 0; o >>= 1) cnt += __shfl_xor(cnt, o);
    return cnt >= 224;
}

// ---------------------------------------------------------------------------
// canonicalize all inputs into packed bf16 region; also writes xpw_pad [64,512]
// ---------------------------------------------------------------------------
struct CanonArgs {
    const void* src[20];
    int off[20];
    int total;
};

__launch_bounds__(256)
__global__ void canon_k(CanonArgs a, ushort* __restrict__ dst, ushort* __restrict__ xpw_pad,
                        const ushort* __restrict__ sniffx)
{
    const int i = blockIdx.x * 256 + threadIdx.x;
    if (i >= a.total) {
        const int j = i - a.total;
        if (j < 8192) xpw_pad[24576 + j] = 0;   // pad rows 48..63
        return;
    }
    const bool fl = sniff_inline(sniffx);
    int s = 0;
    #pragma unroll
    for (int t = 1; t < 20; t++) if (i >= a.off[t]) s = t;
    const int li = i - a.off[s];
    ushort v;
    if (fl) v = ((const ushort*)a.src[s])[li];
    else    v = f2bf(((const float*)a.src[s])[li]);
    dst[i] = v;
    if (s == 5) xpw_pad[li] = v;                // xpw rows 0..47
}

// ---------------------------------------------------------------------------
// in_proj GEMM: xz[8192,1024] = x @ ipw^T + ipb
// ---------------------------------------------------------------------------
template<int BM, int BN>
__launch_bounds__(256, 2)
__global__ void gemm_bt(const ushort* __restrict__ A, const ushort* __restrict__ W,
                        const ushort* __restrict__ bias, ushort* __restrict__ Cb,
                        int N, int K)
{
    constexpr int WMT = BM / 32;
    constexpr int WNT = BN / 32;
    __shared__ __align__(16) ushort As[BM * 32];
    __shared__ __align__(16) ushort Bs[BN * 32];
    const int tid  = threadIdx.x;
    const int wave = tid >> 6;
    const int lane = tid & 63;
    const int m0 = blockIdx.x * BM;
    const int n0 = blockIdx.y * BN;
    const int wm = (wave >> 1) * (BM / 2);
    const int wn = (wave & 1) * (BN / 2);
    const int lrow = lane & 15;
    const int quad = lane >> 4;

    f32x4 acc[WMT][WNT];
    #pragma unroll
    for (int i = 0; i < WMT; i++)
        #pragma unroll
        for (int j = 0; j < WNT; j++)
            #pragma unroll
            for (int r = 0; r < 4; r++) acc[i][j][r] = 0.f;

    for (int k0 = 0; k0 < K; k0 += 32) {
        #pragma unroll
        for (int t = 0; t < BM / 64; t++) {
            const int inst = t * 4 + wave;
            const int row  = inst * 16 + (lane >> 2);
            const int sub  = lane & 3;
            const ushort* gp = A + (size_t)(m0 + row) * K + (k0 + sub * 8);
            __builtin_amdgcn_global_load_lds((AS1 void*)(void*)gp,
                                             (AS3 void*)(As + inst * 512), 16, 0, 0);
        }
        #pragma unroll
        for (int t = 0; t < BN / 64; t++) {
            const int inst = t * 4 + wave;
            const int row  = inst * 16 + (lane >> 2);
            const int sub  = lane & 3;
            const ushort* gp = W + (size_t)(n0 + row) * K + (k0 + sub * 8);
            __builtin_amdgcn_global_load_lds((AS1 void*)(void*)gp,
                                             (AS3 void*)(Bs + inst * 512), 16, 0, 0);
        }
        __syncthreads();
        bf16x8 afr[WMT], bfr[WNT];
        #pragma unroll
        for (int i = 0; i < WMT; i++)
            afr[i] = *(const bf16x8*)&As[(wm + i * 16 + lrow) * 32 + quad * 8];
        #pragma unroll
        for (int j = 0; j < WNT; j++)
            bfr[j] = *(const bf16x8*)&Bs[(wn + j * 16 + lrow) * 32 + quad * 8];
        #pragma unroll
        for (int i = 0; i < WMT; i++)
            #pragma unroll
            for (int j = 0; j < WNT; j++)
                acc[i][j] = __builtin_amdgcn_mfma_f32_16x16x32_bf16(afr[i], bfr[j], acc[i][j], 0, 0, 0);
        __syncthreads();
    }

    #pragma unroll
    for (int i = 0; i < WMT; i++) {
        const int gm = m0 + wm + i * 16 + quad * 4;
        #pragma unroll
        for (int j = 0; j < WNT; j++) {
            const int gn = n0 + wn + j * 16 + lrow;
            const float bv = bf2f(bias[gn]);
            #pragma unroll
            for (int r = 0; r < 4; r++)
                Cb[(size_t)(gm + r) * N + gn] = f2bf(acc[i][j][r] + bv);
        }
    }
}

// ---------------------------------------------------------------------------
// conv+SiLU (16 tokens, LDS) -> xdbl GEMM (LDS A) -> scan pass 1
// grid (128 c, 4 b) x 512 threads  (chunk = 16 tokens -> 2 blocks/CU)
// ---------------------------------------------------------------------------
__launch_bounds__(512)
__global__ void convscan1_k(const ushort* __restrict__ xz, const ushort* __restrict__ cw,
                            const ushort* __restrict__ cb, const ushort* __restrict__ xpw_pad,
                            const ushort* __restrict__ dtw, const ushort* __restrict__ dtb,
                            const ushort* __restrict__ Alog,
                            float* __restrict__ xdbl, float* __restrict__ summ)
{
    __shared__ __align__(16) ushort xcs[16 * 520];
    __shared__ float XD[16 * 48];
    const int tid  = threadIdx.x;
    const int wave = tid >> 6;
    const int lane = tid & 63;
    const int lrow = lane & 15;
    const int quad = lane >> 4;
    const int c = blockIdx.x, b = blockIdx.y;
    const int t0 = b * 2048 + c * 16;

    // ---- conv + silu: thread owns 8 d's x 2 token rows ----
    {
        const int d8 = (tid & 63) * 8;
        ushort wl[32];
        *(uint4*)&wl[0]  = *(const uint4*)&cw[d8 * 4];
        *(uint4*)&wl[8]  = *(const uint4*)&cw[d8 * 4 + 8];
        *(uint4*)&wl[16] = *(const uint4*)&cw[d8 * 4 + 16];
        *(uint4*)&wl[24] = *(const uint4*)&cw[d8 * 4 + 24];
        ushort bl[8];
        *(uint4*)&bl[0] = *(const uint4*)&cb[d8];
        #pragma unroll
        for (int it = 0; it < 2; it++) {
            const int trow = it * 8 + (tid >> 6);
            const int t = t0 + trow;
            const int l = t & 2047;
            float acc[8];
            #pragma unroll
            for (int j = 0; j < 8; j++) acc[j] = bf2f(bl[j]);
            #pragma unroll
            for (int k = 0; k < 4; k++) {
                const int ls = l - 3 + k;
                if (ls >= 0) {
                    ushort xl[8];
                    *(uint4*)&xl[0] = *(const uint4*)&xz[(size_t)(t - 3 + k) * 1024 + d8];
                    #pragma unroll
                    for (int j = 0; j < 8; j++) acc[j] += bf2f(xl[j]) * bf2f(wl[j * 4 + k]);
                }
            }
            ushort ol[8];
            #pragma unroll
            for (int j = 0; j < 8; j++) {
                const float s = acc[j] / (1.f + __expf(-acc[j]));
                ol[j] = f2bf(s);
            }
            *(uint4*)&xcs[trow * 520 + d8] = *(uint4*)&ol[0];
        }
    }
    __syncthreads();

    // ---- xdbl = xcs @ xpw_pad^T: M=16, N=64, K=512; waves 0..3 ----
    if (wave < 4) {
        f32x4 acc = {0.f, 0.f, 0.f, 0.f};
        for (int k0 = 0; k0 < 512; k0 += 32) {
            const bf16x8 afr = *(const bf16x8*)&xcs[lrow * 520 + k0 + quad * 8];
            const bf16x8 bfr = *(const bf16x8*)(xpw_pad + (size_t)(wave * 16 + lrow) * 512 + k0 + quad * 8);
            acc = __builtin_amdgcn_mfma_f32_16x16x32_bf16(afr, bfr, acc, 0, 0, 0);
        }
        const int col = wave * 16 + lrow;
        if (col < 48) {
            #pragma unroll
            for (int r = 0; r < 4; r++) {
                const int row = quad * 4 + r;
                XD[row * 48 + col] = acc[r];
                xdbl[(size_t)(t0 + row) * 64 + col] = acc[r];
            }
        }
    }
    __syncthreads();

    // ---- scan pass 1: thread owns one d (0..511), 16 steps ----
    {
        const int d = tid;
        const uint4 w0 = *(const uint4*)&dtw[d * 16];
        const uint4 w1 = *(const uint4*)&dtw[d * 16 + 8];
        const float wd[16] = { bflo(w0.x), bfhi(w0.x), bflo(w0.y), bfhi(w0.y),
                               bflo(w0.z), bfhi(w0.z), bflo(w0.w), bfhi(w0.w),
                               bflo(w1.x), bfhi(w1.x), bflo(w1.y), bfhi(w1.y),
                               bflo(w1.z), bfhi(w1.z), bflo(w1.w), bfhi(w1.w) };
        const float dtbv = bf2f(dtb[d]);
        float A[16], h[16];
        #pragma unroll
        for (int n = 0; n < 16; n++) {
            A[n] = -__expf(bf2f(Alog[d * 16 + n]));
            h[n] = 0.f;
        }
        float sdt = 0.f;
        for (int i = 0; i < 16; i++) {
            const float* Xr = &XD[i * 48];
            float s = dtbv;
            #pragma unroll
            for (int k = 0; k < 16; k++) s += Xr[k] * wd[k];
            const float dtv = (s > 15.f) ? s : __logf(1.f + __expf(s));
            const float xiv = bf2f(xcs[i * 520 + d]);
            const float dx = dtv * xiv;
            sdt += dtv;
            #pragma unroll
            for (int n = 0; n < 16; n++) {
                const float da = __expf(dtv * A[n]);
                h[n] = da * h[n] + dx * Xr[16 + n];
            }
        }
        const size_t base = ((size_t)(b * 128 + c) * 32) * 512 + d;
        #pragma unroll
        for (int n = 0; n < 16; n++) summ[base + (size_t)n * 512] = __expf(A[n] * sdt);
        #pragma unroll
        for (int n = 0; n < 16; n++) summ[base + (size_t)(16 + n) * 512] = h[n];
    }
}

// sequential combine over 128 chunks, register-batched (4 x 32)
__launch_bounds__(512)
__global__ void combine_k(float* __restrict__ summ)
{
    const int b = blockIdx.x >> 4, n = blockIdx.x & 15;
    const int d = threadIdx.x;
    float h = 0.f;
    #pragma unroll
    for (int batch = 0; batch < 4; batch++) {
        float p[32], hl[32], ho[32];
        #pragma unroll
        for (int c2 = 0; c2 < 32; c2++) {
            const size_t sb = ((size_t)((b * 128 + batch * 32 + c2) * 32 + n)) * 512 + d;
            p[c2]  = summ[sb];
            hl[c2] = summ[sb + 8192];
        }
        #pragma unroll
        for (int c2 = 0; c2 < 32; c2++) {
            ho[c2] = h;
            h = p[c2] * h + hl[c2];
        }
        #pragma unroll
        for (int c2 = 0; c2 < 32; c2++) {
            const size_t sb = ((size_t)((b * 128 + batch * 32 + c2) * 32 + n)) * 512 + d;
            summ[sb] = ho[c2];
        }
    }
}

// ---------------------------------------------------------------------------
// tail (chunk = 16 tokens): conv -> scan2 (y into LDS) -> out_proj+LN1 ->
// 4x(fc1 -> fc2 partial) -> gelu+resid -> LN2 -> d_out.  grid (128,4) x 512
// ---------------------------------------------------------------------------
__launch_bounds__(512)
__global__ void tail_k(const ushort* __restrict__ xz, const ushort* __restrict__ cw,
                       const ushort* __restrict__ cb, const float* __restrict__ xdbl,
                       const ushort* __restrict__ dtw, const ushort* __restrict__ dtb,
                       const ushort* __restrict__ Alog, const float* __restrict__ summ,
                       const ushort* __restrict__ Dssm, const ushort* __restrict__ cx,
                       const ushort* __restrict__ opw, const ushort* __restrict__ opb,
                       const ushort* __restrict__ ln1g, const ushort* __restrict__ ln1b,
                       const ushort* __restrict__ f1w, const ushort* __restrict__ f1b,
                       const ushort* __restrict__ f2w, const ushort* __restrict__ f2b,
                       const ushort* __restrict__ ln2g, const ushort* __restrict__ ln2b,
                       void* __restrict__ dout, const ushort* __restrict__ sniffx)
{
    __shared__ __align__(16) ushort yls[16 * 520];   // xi -> y (in place); later f1q
    __shared__ float XD[16 * 48];
    __shared__ __align__(16) ushort y1bs[16 * 264];
    __shared__ float redS[8 * 16], redQ[8 * 16];
    ushort* f1q = yls;                                // alias (stride 260, y dead)

    const int tid  = threadIdx.x;
    const int wave = tid >> 6;
    const int lane = tid & 63;
    const int lrow = lane & 15;
    const int quad = lane >> 4;
    const int c = blockIdx.x, b = blockIdx.y;
    const int t0 = b * 2048 + c * 16;
    const int n0w = wave * 32;           // this wave's 32-col slice

    // ---- conv + silu ----
    {
        const int d8 = (tid & 63) * 8;
        ushort wl[32];
        *(uint4*)&wl[0]  = *(const uint4*)&cw[d8 * 4];
        *(uint4*)&wl[8]  = *(const uint4*)&cw[d8 * 4 + 8];
        *(uint4*)&wl[16] = *(const uint4*)&cw[d8 * 4 + 16];
        *(uint4*)&wl[24] = *(const uint4*)&cw[d8 * 4 + 24];
        ushort bl[8];
        *(uint4*)&bl[0] = *(const uint4*)&cb[d8];
        #pragma unroll
        for (int it = 0; it < 2; it++) {
            const int trow = it * 8 + (tid >> 6);
            const int t = t0 + trow;
            const int l = t & 2047;
            float acc[8];
            #pragma unroll
            for (int j = 0; j < 8; j++) acc[j] = bf2f(bl[j]);
            #pragma unroll
            for (int k = 0; k < 4; k++) {
                const int ls = l - 3 + k;
                if (ls >= 0) {
                    ushort xl[8];
                    *(uint4*)&xl[0] = *(const uint4*)&xz[(size_t)(t - 3 + k) * 1024 + d8];
                    #pragma unroll
                    for (int j = 0; j < 8; j++) acc[j] += bf2f(xl[j]) * bf2f(wl[j * 4 + k]);
                }
            }
            ushort ol[8];
            #pragma unroll
            for (int j = 0; j < 8; j++) {
                const float s = acc[j] / (1.f + __expf(-acc[j]));
                ol[j] = f2bf(s);
            }
            *(uint4*)&yls[trow * 520 + d8] = *(uint4*)&ol[0];
        }
    }
    for (int e = tid; e < 768; e += 512)
        XD[e] = xdbl[(size_t)(t0 + (e / 48)) * 64 + (e % 48)];
    __syncthreads();

    // ---- scan pass 2: thread owns one d; y overwrites xi in LDS ----
    {
        const int d = tid;
        const uint4 w0 = *(const uint4*)&dtw[d * 16];
        const uint4 w1 = *(const uint4*)&dtw[d * 16 + 8];
        const float wd[16] = { bflo(w0.x), bfhi(w0.x), bflo(w0.y), bfhi(w0.y),
                               bflo(w0.z), bfhi(w0.z), bflo(w0.w), bfhi(w0.w),
                               bflo(w1.x), bfhi(w1.x), bflo(w1.y), bfhi(w1.y),
                               bflo(w1.z), bfhi(w1.z), bflo(w1.w), bfhi(w1.w) };
        const float dtbv = bf2f(dtb[d]);
        float A[16], h[16];
        #pragma unroll
        for (int n = 0; n < 16; n++) A[n] = -__expf(bf2f(Alog[d * 16 + n]));
        const size_t base = ((size_t)(b * 128 + c) * 32) * 512 + d;
        #pragma unroll
        for (int n = 0; n < 16; n++) h[n] = summ[base + (size_t)n * 512];
        const float Dv = bf2f(Dssm[d]);
        for (int i = 0; i < 16; i++) {
            const int t = t0 + i;
            const float* Xr = &XD[i * 48];
            float s = dtbv;
            #pragma unroll
            for (int k = 0; k < 16; k++) s += Xr[k] * wd[k];
            const float dtv = (s > 15.f) ? s : __logf(1.f + __expf(s));
            const float xiv = bf2f(yls[i * 520 + d]);
            const float dx = dtv * xiv;
            float yv = 0.f;
            #pragma unroll
            for (int n = 0; n < 16; n++) {
                const float da = __expf(dtv * A[n]);
                h[n] = da * h[n] + dx * Xr[16 + n];
                yv += h[n] * Xr[32 + n];
            }
            yv += xiv * Dv;
            const float zv = bf2f(xz[(size_t)t * 1024 + 512 + d]);
            yv *= zv / (1.f + __expf(-zv));
            yls[i * 520 + d] = f2bf(yv);   // in-place (same thread, same slot)
        }
    }
    __syncthreads();

    // ---- out_proj: M=16, N=256, K=512 from LDS y; wave -> cols n0w..n0w+31 ----
    f32x4 accP[2];
    #pragma unroll
    for (int j = 0; j < 2; j++)
        #pragma unroll
        for (int r = 0; r < 4; r++) accP[j][r] = 0.f;
    for (int k0 = 0; k0 < 512; k0 += 32) {
        const bf16x8 afr = *(const bf16x8*)&yls[lrow * 520 + k0 + quad * 8];
        #pragma unroll
        for (int j = 0; j < 2; j++) {
            const bf16x8 bfr = *(const bf16x8*)(opw + (size_t)(n0w + j * 16 + lrow) * 512 + k0 + quad * 8);
            accP[j] = __builtin_amdgcn_mfma_f32_16x16x32_bf16(afr, bfr, accP[j], 0, 0, 0);
        }
    }
    // epilogue + LN1 partials
    float vP[2][4];
    float ps[4], pq[4];
    #pragma unroll
    for (int r = 0; r < 4; r++) { ps[r] = 0.f; pq[r] = 0.f; }
    #pragma unroll
    for (int j = 0; j < 2; j++) {
        const int col = n0w + j * 16 + lrow;
        const float bv = bf2f(opb[col]);
        #pragma unroll
        for (int r = 0; r < 4; r++) {
            const int row = quad * 4 + r;
            float v = accP[j][r] + bv + bf2f(cx[(size_t)(t0 + row) * 256 + col]);
            vP[j][r] = v;
            ps[r] += v;
            pq[r] += v * v;
        }
    }
    #pragma unroll
    for (int r = 0; r < 4; r++) {
        #pragma unroll
        for (int o = 8; o > 0; o >>= 1) {
            ps[r] += __shfl_xor(ps[r], o);
            pq[r] += __shfl_xor(pq[r], o);
        }
        if (lrow == 0) {
            const int row = quad * 4 + r;
            redS[wave * 16 + row] = ps[r];
            redQ[wave * 16 + row] = pq[r];
        }
    }
    __syncthreads();

    // LN1 -> y1bs (bf16) + y1f in registers
    float y1f[2][4];
    #pragma unroll
    for (int r = 0; r < 4; r++) {
        const int row = quad * 4 + r;
        float S = 0.f, Q = 0.f;
        #pragma unroll
        for (int w = 0; w < 8; w++) { S += redS[w * 16 + row]; Q += redQ[w * 16 + row]; }
        const float mean = S * (1.f / 256.f);
        const float var  = Q * (1.f / 256.f) - mean * mean;
        const float rs   = rsqrtf(var + 1e-5f);
        #pragma unroll
        for (int j = 0; j < 2; j++) {
            const int col = n0w + j * 16 + lrow;
            const float o2 = (vP[j][r] - mean) * rs * bf2f(ln1g[col]) + bf2f(ln1b[col]);
            y1f[j][r] = o2;
            y1bs[row * 264 + col] = f2bf(o2);
        }
    }
    __syncthreads();

    // ---- fc1 (4 col-quarters) + fc2 partial-K accumulate ----
    f32x4 acc2[2];
    #pragma unroll
    for (int j = 0; j < 2; j++)
        #pragma unroll
        for (int r = 0; r < 4; r++) acc2[j][r] = 0.f;

    for (int q = 0; q < 4; q++) {
        f32x4 a1[2];
        #pragma unroll
        for (int j = 0; j < 2; j++)
            #pragma unroll
            for (int r = 0; r < 4; r++) a1[j][r] = 0.f;
        for (int k0 = 0; k0 < 256; k0 += 32) {
            const bf16x8 afr = *(const bf16x8*)&y1bs[lrow * 264 + k0 + quad * 8];
            #pragma unroll
            for (int j = 0; j < 2; j++) {
                const bf16x8 bfr = *(const bf16x8*)(f1w + (size_t)(q * 256 + n0w + j * 16 + lrow) * 256 + k0 + quad * 8);
                a1[j] = __builtin_amdgcn_mfma_f32_16x16x32_bf16(afr, bfr, a1[j], 0, 0, 0);
            }
        }
        #pragma unroll
        for (int j = 0; j < 2; j++) {
            const int qc = n0w + j * 16 + lrow;
            const float bv = bf2f(f1b[q * 256 + qc]);
            #pragma unroll
            for (int r = 0; r < 4; r++) {
                const int row = quad * 4 + r;
                f1q[row * 260 + qc] = f2bf(gelu_f(a1[j][r] + bv));
            }
        }
        __syncthreads();
        for (int k0 = 0; k0 < 256; k0 += 32) {
            const bf16x8 afr = *(const bf16x8*)&f1q[lrow * 260 + k0 + quad * 8];
            #pragma unroll
            for (int j = 0; j < 2; j++) {
                const bf16x8 bfr = *(const bf16x8*)(f2w + (size_t)(n0w + j * 16 + lrow) * 1024 + q * 256 + k0 + quad * 8);
                acc2[j] = __builtin_amdgcn_mfma_f32_16x16x32_bf16(afr, bfr, acc2[j], 0, 0, 0);
            }
        }
        __syncthreads();
    }

    // ---- fc2 epilogue: gelu + resid y1f, LN2, write d_out ----
    float v2[2][4];
    #pragma unroll
    for (int r = 0; r < 4; r++) { ps[r] = 0.f; pq[r] = 0.f; }
    #pragma unroll
    for (int j = 0; j < 2; j++) {
        const int col = n0w + j * 16 + lrow;
        const float bv = bf2f(f2b[col]);
        #pragma unroll
        for (int r = 0; r < 4; r++) {
            const float v = gelu_f(acc2[j][r] + bv) + y1f[j][r];
            v2[j][r] = v;
            ps[r] += v;
            pq[r] += v * v;
        }
    }
    #pragma unroll
    for (int r = 0; r < 4; r++) {
        #pragma unroll
        for (int o = 8; o > 0; o >>= 1) {
            ps[r] += __shfl_xor(ps[r], o);
            pq[r] += __shfl_xor(pq[r], o);
        }
        if (lrow == 0) {
            const int row = quad * 4 + r;
            redS[wave * 16 + row] = ps[r];
            redQ[wave * 16 + row] = pq[r];
        }
    }
    __syncthreads();

    const bool fl = sniff_inline(sniffx);
    #pragma unroll
    for (int r = 0; r < 4; r++) {
        const int row = quad * 4 + r;
        float S = 0.f, Q = 0.f;
        #pragma unroll
        for (int w = 0; w < 8; w++) { S += redS[w * 16 + row]; Q += redQ[w * 16 + row]; }
        const float mean = S * (1.f / 256.f);
        const float var  = Q * (1.f / 256.f) - mean * mean;
        const float rs   = rsqrtf(var + 1e-5f);
        #pragma unroll
        for (int j = 0; j < 2; j++) {
            const int col = n0w + j * 16 + lrow;
            const size_t off = (size_t)(t0 + row) * 256 + col;
            const float o2 = (v2[j][r] - mean) * rs * bf2f(ln2g[col]) + bf2f(ln2b[col]);
            if (fl) ((ushort*)dout)[off] = f2bf(o2);
            else    ((float*)dout)[off]  = o2;
        }
    }
}

// ---------------------------------------------------------------------------
extern "C" void kernel_launch(void* const* d_in, const int* in_sizes, int n_in,
                              void* d_out, int out_size, void* d_ws, size_t ws_size,
                              hipStream_t stream)
{
    char* ws = (char*)d_ws;
    ushort* canon = (ushort*)(ws + 256);

    static const int coff[20] = {
        0,        2097152,  2359296,  2360320,  2362368,
        2362880,  2387456,  2395648,  2396160,  2404352,
        2404864,  2535936,  2536192,  2536448,  2536704,
        2798848,  2799872,  3062016,  3062272,  3062528 };
    static const int ctot = 3062784;

    CanonArgs ca;
    for (int i = 0; i < 20; i++) { ca.src[i] = d_in[i]; ca.off[i] = coff[i]; }
    ca.total = ctot;

    const ushort* cx   = canon + coff[0];
    const ushort* cipw = canon + coff[1];
    const ushort* cipb = canon + coff[2];
    const ushort* ccw  = canon + coff[3];
    const ushort* ccb  = canon + coff[4];
    const ushort* cdtw = canon + coff[6];
    const ushort* cdtb = canon + coff[7];
    const ushort* calog= canon + coff[8];
    const ushort* cdssm= canon + coff[9];
    const ushort* copw = canon + coff[10];
    const ushort* copb = canon + coff[11];
    const ushort* cln1g= canon + coff[12];
    const ushort* cln1b= canon + coff[13];
    const ushort* cf1w = canon + coff[14];
    const ushort* cf1b = canon + coff[15];
    const ushort* cf2w = canon + coff[16];
    const ushort* cf2b = canon + coff[17];
    const ushort* cln2g= canon + coff[18];
    const ushort* cln2b= canon + coff[19];

    ushort* xpw_pad = (ushort*)(ws + 6291456);  // [64,512] bf16
    ushort* xz      = (ushort*)(ws + 8388608);  // [8192,1024] bf16, 16 MB
    float*  xdbl    = (float*)(ws + 25165824);  // [8192,64] f32, 2 MB
    float*  summ    = (float*)(ws + 27262976);  // [4,128,32,512] f32, 33.5 MB
    const ushort* sx = (const ushort*)d_in[0];

    // 1. canon + xpw padding
    canon_k<<<(ctot + 8192 + 255) / 256, 256, 0, stream>>>(ca, canon, xpw_pad, sx);
    // 2. in_proj: xz = x @ ipw^T + ipb
    gemm_bt<128, 128><<<dim3(64, 8), 256, 0, stream>>>(cx, cipw, cipb, xz, 1024, 256);
    // 3. conv + silu + xdbl + scan1 (fused, 16-token chunks, 512 blocks)
    convscan1_k<<<dim3(128, 4), 512, 0, stream>>>(
        xz, ccw, ccb, xpw_pad, cdtw, cdtb, calog, xdbl, summ);
    // 4. combine (128 chunk-boundary states)
    combine_k<<<64, 512, 0, stream>>>(summ);
    // 5. tail: scan2 + out_proj + LN1 + fc1 + fc2 + LN2 -> d_out (512 blocks)
    tail_k<<<dim3(128, 4), 512, 0, stream>>>(
        xz, ccw, ccb, xdbl, cdtw, cdtb, calog, summ, cdssm, cx,
        copw, copb, cln1g, cln1b, cf1w, cf1b, cf2w, cf2b, cln2g, cln2b,
        d_out, sx);
}

// Round 12
// 235.177 us; speedup vs baseline: 1.1022x; 1.1022x over previous
//
#include <hip/hip_runtime.h>

typedef __bf16 bf16x8 __attribute__((ext_vector_type(8)));
typedef float  f32x4  __attribute__((ext_vector_type(4)));

#define AS1 __attribute__((address_space(1)))
#define AS3 __attribute__((address_space(3)))

__device__ __forceinline__ float bf2f(ushort u) {
    union { unsigned int i; float f; } v; v.i = ((unsigned int)u) << 16; return v.f;
}
__device__ __forceinline__ ushort f2bf(float f) {
    union { float f; unsigned int i; } v; v.f = f;
    unsigned int i = v.i;
    unsigned int r = i + 0x7FFFu + ((i >> 16) & 1u);   // RNE
    return (ushort)(r >> 16);
}
__device__ __forceinline__ float bflo(unsigned int u) { return bf2f((ushort)(u & 0xFFFFu)); }
__device__ __forceinline__ float bfhi(unsigned int u) { return bf2f((ushort)(u >> 16)); }
__device__ __forceinline__ float gelu_f(float v) {
    return 0.5f * v * (1.f + erff(v * 0.70710678118654752f));
}

// wave-level inline dtype sniff: 1 = bf16 inputs, 0 = f32
__device__ __forceinline__ bool sniff_inline(const ushort* __restrict__ x) {
    const int lane = threadIdx.x & 63;
    int cnt = 0;
    #pragma unroll
    for (int r = 0; r < 4; r++) {
        const ushort u = x[lane + r * 64];
        const int e = (u >> 7) & 0xFF;
        if ((u & 0x7FFF) == 0 || (e >= 112 && e <= 141)) cnt++;
    }
    #pragma unroll
    for (int o = 32; o > 0; o >>= 1) cnt += __shfl_xor(cnt, o);
    return cnt >= 224;
}

// ---------------------------------------------------------------------------
// canonicalize all inputs into packed bf16 region; also writes xpw_pad [64,512]
// ---------------------------------------------------------------------------
struct CanonArgs {
    const void* src[20];
    int off[20];
    int total;
};

__launch_bounds__(256)
__global__ void canon_k(CanonArgs a, ushort* __restrict__ dst, ushort* __restrict__ xpw_pad,
                        const ushort* __restrict__ sniffx)
{
    const int i = blockIdx.x * 256 + threadIdx.x;
    if (i >= a.total) {
        const int j = i - a.total;
        if (j < 8192) xpw_pad[24576 + j] = 0;   // pad rows 48..63
        return;
    }
    const bool fl = sniff_inline(sniffx);
    int s = 0;
    #pragma unroll
    for (int t = 1; t < 20; t++) if (i >= a.off[t]) s = t;
    const int li = i - a.off[s];
    ushort v;
    if (fl) v = ((const ushort*)a.src[s])[li];
    else    v = f2bf(((const float*)a.src[s])[li]);
    dst[i] = v;
    if (s == 5) xpw_pad[li] = v;                // xpw rows 0..47
}

// ---------------------------------------------------------------------------
// in_proj GEMM: xz[8192,1024] = x @ ipw^T + ipb
// ---------------------------------------------------------------------------
template<int BM, int BN>
__launch_bounds__(256, 2)
__global__ void gemm_bt(const ushort* __restrict__ A, const ushort* __restrict__ W,
                        const ushort* __restrict__ bias, ushort* __restrict__ Cb,
                        int N, int K)
{
    constexpr int WMT = BM / 32;
    constexpr int WNT = BN / 32;
    __shared__ __align__(16) ushort As[BM * 32];
    __shared__ __align__(16) ushort Bs[BN * 32];
    const int tid  = threadIdx.x;
    const int wave = tid >> 6;
    const int lane = tid & 63;
    const int m0 = blockIdx.x * BM;
    const int n0 = blockIdx.y * BN;
    const int wm = (wave >> 1) * (BM / 2);
    const int wn = (wave & 1) * (BN / 2);
    const int lrow = lane & 15;
    const int quad = lane >> 4;

    f32x4 acc[WMT][WNT];
    #pragma unroll
    for (int i = 0; i < WMT; i++)
        #pragma unroll
        for (int j = 0; j < WNT; j++)
            #pragma unroll
            for (int r = 0; r < 4; r++) acc[i][j][r] = 0.f;

    for (int k0 = 0; k0 < K; k0 += 32) {
        #pragma unroll
        for (int t = 0; t < BM / 64; t++) {
            const int inst = t * 4 + wave;
            const int row  = inst * 16 + (lane >> 2);
            const int sub  = lane & 3;
            const ushort* gp = A + (size_t)(m0 + row) * K + (k0 + sub * 8);
            __builtin_amdgcn_global_load_lds((AS1 void*)(void*)gp,
                                             (AS3 void*)(As + inst * 512), 16, 0, 0);
        }
        #pragma unroll
        for (int t = 0; t < BN / 64; t++) {
            const int inst = t * 4 + wave;
            const int row  = inst * 16 + (lane >> 2);
            const int sub  = lane & 3;
            const ushort* gp = W + (size_t)(n0 + row) * K + (k0 + sub * 8);
            __builtin_amdgcn_global_load_lds((AS1 void*)(void*)gp,
                                             (AS3 void*)(Bs + inst * 512), 16, 0, 0);
        }
        __syncthreads();
        bf16x8 afr[WMT], bfr[WNT];
        #pragma unroll
        for (int i = 0; i < WMT; i++)
            afr[i] = *(const bf16x8*)&As[(wm + i * 16 + lrow) * 32 + quad * 8];
        #pragma unroll
        for (int j = 0; j < WNT; j++)
            bfr[j] = *(const bf16x8*)&Bs[(wn + j * 16 + lrow) * 32 + quad * 8];
        #pragma unroll
        for (int i = 0; i < WMT; i++)
            #pragma unroll
            for (int j = 0; j < WNT; j++)
                acc[i][j] = __builtin_amdgcn_mfma_f32_16x16x32_bf16(afr[i], bfr[j], acc[i][j], 0, 0, 0);
        __syncthreads();
    }

    #pragma unroll
    for (int i = 0; i < WMT; i++) {
        const int gm = m0 + wm + i * 16 + quad * 4;
        #pragma unroll
        for (int j = 0; j < WNT; j++) {
            const int gn = n0 + wn + j * 16 + lrow;
            const float bv = bf2f(bias[gn]);
            #pragma unroll
            for (int r = 0; r < 4; r++)
                Cb[(size_t)(gm + r) * N + gn] = f2bf(acc[i][j][r] + bv);
        }
    }
}

// ---------------------------------------------------------------------------
// conv+SiLU (32 tokens, LDS) -> xdbl GEMM (LDS A, prefetched L2 B) -> scan1
// grid (64 c, 4 b) x 512 threads
// ---------------------------------------------------------------------------
__launch_bounds__(512)
__global__ void convscan1_k(const ushort* __restrict__ xz, const ushort* __restrict__ cw,
                            const ushort* __restrict__ cb, const ushort* __restrict__ xpw_pad,
                            const ushort* __restrict__ dtw, const ushort* __restrict__ dtb,
                            const ushort* __restrict__ Alog,
                            float* __restrict__ xdbl, float* __restrict__ summ)
{
    __shared__ __align__(16) ushort xcs[32 * 520];
    __shared__ float XD[32 * 48];
    const int tid  = threadIdx.x;
    const int wave = tid >> 6;
    const int lane = tid & 63;
    const int lrow = lane & 15;
    const int quad = lane >> 4;
    const int c = blockIdx.x, b = blockIdx.y;
    const int t0 = b * 2048 + c * 32;

    // ---- conv + silu ----
    {
        const int d8 = (tid & 63) * 8;
        ushort wl[32];
        *(uint4*)&wl[0]  = *(const uint4*)&cw[d8 * 4];
        *(uint4*)&wl[8]  = *(const uint4*)&cw[d8 * 4 + 8];
        *(uint4*)&wl[16] = *(const uint4*)&cw[d8 * 4 + 16];
        *(uint4*)&wl[24] = *(const uint4*)&cw[d8 * 4 + 24];
        ushort bl[8];
        *(uint4*)&bl[0] = *(const uint4*)&cb[d8];
        #pragma unroll
        for (int it = 0; it < 4; it++) {
            const int trow = it * 8 + (tid >> 6);
            const int t = t0 + trow;
            const int l = t & 2047;
            float acc[8];
            #pragma unroll
            for (int j = 0; j < 8; j++) acc[j] = bf2f(bl[j]);
            #pragma unroll
            for (int k = 0; k < 4; k++) {
                const int ls = l - 3 + k;
                if (ls >= 0) {
                    ushort xl[8];
                    *(uint4*)&xl[0] = *(const uint4*)&xz[(size_t)(t - 3 + k) * 1024 + d8];
                    #pragma unroll
                    for (int j = 0; j < 8; j++) acc[j] += bf2f(xl[j]) * bf2f(wl[j * 4 + k]);
                }
            }
            ushort ol[8];
            #pragma unroll
            for (int j = 0; j < 8; j++) {
                const float s = acc[j] / (1.f + __expf(-acc[j]));
                ol[j] = f2bf(s);
            }
            *(uint4*)&xcs[trow * 520 + d8] = *(uint4*)&ol[0];
        }
    }
    __syncthreads();

    // ---- xdbl = xcs @ xpw_pad^T: M=32, N=64, K=512; B prefetched ----
    {
        const int mt = wave >> 2, nt = wave & 3;
        const ushort* bptr = xpw_pad + (size_t)(nt * 16 + lrow) * 512 + quad * 8;
        f32x4 acc = {0.f, 0.f, 0.f, 0.f};
        bf16x8 bn = *(const bf16x8*)bptr;
        for (int k0 = 0; k0 < 512; k0 += 32) {
            const bf16x8 bc = bn;
            if (k0 + 32 < 512) bn = *(const bf16x8*)(bptr + k0 + 32);
            const bf16x8 afr = *(const bf16x8*)&xcs[(mt * 16 + lrow) * 520 + k0 + quad * 8];
            acc = __builtin_amdgcn_mfma_f32_16x16x32_bf16(afr, bc, acc, 0, 0, 0);
        }
        const int col = nt * 16 + lrow;
        if (col < 48) {
            #pragma unroll
            for (int r = 0; r < 4; r++) {
                const int row = mt * 16 + quad * 4 + r;
                XD[row * 48 + col] = acc[r];
                xdbl[(size_t)(t0 + row) * 64 + col] = acc[r];
            }
        }
    }
    __syncthreads();

    // ---- scan pass 1: thread owns one d ----
    {
        const int d = tid;
        const uint4 w0 = *(const uint4*)&dtw[d * 16];
        const uint4 w1 = *(const uint4*)&dtw[d * 16 + 8];
        const float wd[16] = { bflo(w0.x), bfhi(w0.x), bflo(w0.y), bfhi(w0.y),
                               bflo(w0.z), bfhi(w0.z), bflo(w0.w), bfhi(w0.w),
                               bflo(w1.x), bfhi(w1.x), bflo(w1.y), bfhi(w1.y),
                               bflo(w1.z), bfhi(w1.z), bflo(w1.w), bfhi(w1.w) };
        const float dtbv = bf2f(dtb[d]);
        float A[16], h[16];
        #pragma unroll
        for (int n = 0; n < 16; n++) {
            A[n] = -__expf(bf2f(Alog[d * 16 + n]));
            h[n] = 0.f;
        }
        float sdt = 0.f;
        for (int i = 0; i < 32; i++) {
            const float* Xr = &XD[i * 48];
            float s = dtbv;
            #pragma unroll
            for (int k = 0; k < 16; k++) s += Xr[k] * wd[k];
            const float dtv = (s > 15.f) ? s : __logf(1.f + __expf(s));
            const float xiv = bf2f(xcs[i * 520 + d]);
            const float dx = dtv * xiv;
            sdt += dtv;
            #pragma unroll
            for (int n = 0; n < 16; n++) {
                const float da = __expf(dtv * A[n]);
                h[n] = da * h[n] + dx * Xr[16 + n];
            }
        }
        const size_t base = ((size_t)(b * 64 + c) * 32) * 512 + d;
        #pragma unroll
        for (int n = 0; n < 16; n++) summ[base + (size_t)n * 512] = __expf(A[n] * sdt);
        #pragma unroll
        for (int n = 0; n < 16; n++) summ[base + (size_t)(16 + n) * 512] = h[n];
    }
}

// sequential combine, register-batched; overwrites p-slot with h_in
__launch_bounds__(512)
__global__ void combine_k(float* __restrict__ summ)
{
    const int b = blockIdx.x >> 4, n = blockIdx.x & 15;
    const int d = threadIdx.x;
    float h = 0.f;
    #pragma unroll
    for (int half = 0; half < 2; half++) {
        float p[32], hl[32], ho[32];
        #pragma unroll
        for (int c2 = 0; c2 < 32; c2++) {
            const size_t sb = ((size_t)((b * 64 + half * 32 + c2) * 32 + n)) * 512 + d;
            p[c2]  = summ[sb];
            hl[c2] = summ[sb + 8192];
        }
        #pragma unroll
        for (int c2 = 0; c2 < 32; c2++) {
            ho[c2] = h;
            h = p[c2] * h + hl[c2];
        }
        #pragma unroll
        for (int c2 = 0; c2 < 32; c2++) {
            const size_t sb = ((size_t)((b * 64 + half * 32 + c2) * 32 + n)) * 512 + d;
            summ[sb] = ho[c2];
        }
    }
}

// ---------------------------------------------------------------------------
// tail (chunk = 32 tokens, R9 structure): conv -> scan2 (y into LDS) ->
// out_proj+LN1 -> 4x(fc1 -> fc2 partial) -> gelu+resid -> LN2 -> d_out.
// grid (64,4) x 512.  B-weights register-prefetched one k-iter ahead
// (thread-local change only vs R9).
// ---------------------------------------------------------------------------
__launch_bounds__(512)
__global__ void tail_k(const ushort* __restrict__ xz, const ushort* __restrict__ cw,
                       const ushort* __restrict__ cb, const float* __restrict__ xdbl,
                       const ushort* __restrict__ dtw, const ushort* __restrict__ dtb,
                       const ushort* __restrict__ Alog, const float* __restrict__ summ,
                       const ushort* __restrict__ Dssm, const ushort* __restrict__ cx,
                       const ushort* __restrict__ opw, const ushort* __restrict__ opb,
                       const ushort* __restrict__ ln1g, const ushort* __restrict__ ln1b,
                       const ushort* __restrict__ f1w, const ushort* __restrict__ f1b,
                       const ushort* __restrict__ f2w, const ushort* __restrict__ f2b,
                       const ushort* __restrict__ ln2g, const ushort* __restrict__ ln2b,
                       void* __restrict__ dout, const ushort* __restrict__ sniffx)
{
    __shared__ __align__(16) ushort yls[32 * 520];   // xi -> y (in place); later f1q
    __shared__ float XD[32 * 48];
    __shared__ __align__(16) ushort y1bs[32 * 264];
    __shared__ float redS[8 * 32], redQ[8 * 32];
    ushort* f1q = yls;                                // alias (stride 260, y dead)

    const int tid  = threadIdx.x;
    const int wave = tid >> 6;
    const int lane = tid & 63;
    const int lrow = lane & 15;
    const int quad = lane >> 4;
    const int c = blockIdx.x, b = blockIdx.y;
    const int t0 = b * 2048 + c * 32;
    const int n0w = wave * 32;

    // ---- conv + silu ----
    {
        const int d8 = (tid & 63) * 8;
        ushort wl[32];
        *(uint4*)&wl[0]  = *(const uint4*)&cw[d8 * 4];
        *(uint4*)&wl[8]  = *(const uint4*)&cw[d8 * 4 + 8];
        *(uint4*)&wl[16] = *(const uint4*)&cw[d8 * 4 + 16];
        *(uint4*)&wl[24] = *(const uint4*)&cw[d8 * 4 + 24];
        ushort bl[8];
        *(uint4*)&bl[0] = *(const uint4*)&cb[d8];
        #pragma unroll
        for (int it = 0; it < 4; it++) {
            const int trow = it * 8 + (tid >> 6);
            const int t = t0 + trow;
            const int l = t & 2047;
            float acc[8];
            #pragma unroll
            for (int j = 0; j < 8; j++) acc[j] = bf2f(bl[j]);
            #pragma unroll
            for (int k = 0; k < 4; k++) {
                const int ls = l - 3 + k;
                if (ls >= 0) {
                    ushort xl[8];
                    *(uint4*)&xl[0] = *(const uint4*)&xz[(size_t)(t - 3 + k) * 1024 + d8];
                    #pragma unroll
                    for (int j = 0; j < 8; j++) acc[j] += bf2f(xl[j]) * bf2f(wl[j * 4 + k]);
                }
            }
            ushort ol[8];
            #pragma unroll
            for (int j = 0; j < 8; j++) {
                const float s = acc[j] / (1.f + __expf(-acc[j]));
                ol[j] = f2bf(s);
            }
            *(uint4*)&yls[trow * 520 + d8] = *(uint4*)&ol[0];
        }
    }
    for (int e = tid; e < 1536; e += 512)
        XD[e] = xdbl[(size_t)(t0 + (e / 48)) * 64 + (e % 48)];
    __syncthreads();

    // ---- scan pass 2: thread owns one d; y overwrites xi in LDS ----
    {
        const int d = tid;
        const uint4 w0 = *(const uint4*)&dtw[d * 16];
        const uint4 w1 = *(const uint4*)&dtw[d * 16 + 8];
        const float wd[16] = { bflo(w0.x), bfhi(w0.x), bflo(w0.y), bfhi(w0.y),
                               bflo(w0.z), bfhi(w0.z), bflo(w0.w), bfhi(w0.w),
                               bflo(w1.x), bfhi(w1.x), bflo(w1.y), bfhi(w1.y),
                               bflo(w1.z), bfhi(w1.z), bflo(w1.w), bfhi(w1.w) };
        const float dtbv = bf2f(dtb[d]);
        float A[16], h[16];
        #pragma unroll
        for (int n = 0; n < 16; n++) A[n] = -__expf(bf2f(Alog[d * 16 + n]));
        const size_t base = ((size_t)(b * 64 + c) * 32) * 512 + d;
        #pragma unroll
        for (int n = 0; n < 16; n++) h[n] = summ[base + (size_t)n * 512];
        const float Dv = bf2f(Dssm[d]);
        for (int i = 0; i < 32; i++) {
            const int t = t0 + i;
            const float* Xr = &XD[i * 48];
            float s = dtbv;
            #pragma unroll
            for (int k = 0; k < 16; k++) s += Xr[k] * wd[k];
            const float dtv = (s > 15.f) ? s : __logf(1.f + __expf(s));
            const float xiv = bf2f(yls[i * 520 + d]);
            const float dx = dtv * xiv;
            float yv = 0.f;
            #pragma unroll
            for (int n = 0; n < 16; n++) {
                const float da = __expf(dtv * A[n]);
                h[n] = da * h[n] + dx * Xr[16 + n];
                yv += h[n] * Xr[32 + n];
            }
            yv += xiv * Dv;
            const float zv = bf2f(xz[(size_t)t * 1024 + 512 + d]);
            yv *= zv / (1.f + __expf(-zv));
            yls[i * 520 + d] = f2bf(yv);   // in-place (same thread, same slot)
        }
    }
    __syncthreads();

    // ---- out_proj: M=32, N=256, K=512 from LDS y; B prefetched ----
    f32x4 accP[2][2];
    #pragma unroll
    for (int i = 0; i < 2; i++)
        #pragma unroll
        for (int j = 0; j < 2; j++)
            #pragma unroll
            for (int r = 0; r < 4; r++) accP[i][j][r] = 0.f;
    {
        const ushort* bp0 = opw + (size_t)(n0w + lrow) * 512 + quad * 8;
        const ushort* bp1 = opw + (size_t)(n0w + 16 + lrow) * 512 + quad * 8;
        bf16x8 bn0 = *(const bf16x8*)bp0;
        bf16x8 bn1 = *(const bf16x8*)bp1;
        for (int k0 = 0; k0 < 512; k0 += 32) {
            const bf16x8 bc0 = bn0, bc1 = bn1;
            if (k0 + 32 < 512) {
                bn0 = *(const bf16x8*)(bp0 + k0 + 32);
                bn1 = *(const bf16x8*)(bp1 + k0 + 32);
            }
            bf16x8 afr[2];
            #pragma unroll
            for (int i = 0; i < 2; i++)
                afr[i] = *(const bf16x8*)&yls[(i * 16 + lrow) * 520 + k0 + quad * 8];
            #pragma unroll
            for (int i = 0; i < 2; i++) {
                accP[i][0] = __builtin_amdgcn_mfma_f32_16x16x32_bf16(afr[i], bc0, accP[i][0], 0, 0, 0);
                accP[i][1] = __builtin_amdgcn_mfma_f32_16x16x32_bf16(afr[i], bc1, accP[i][1], 0, 0, 0);
            }
        }
    }
    // epilogue + LN1 partials
    float vP[2][2][4];
    float ps[2][4], pq[2][4];
    #pragma unroll
    for (int i = 0; i < 2; i++)
        #pragma unroll
        for (int r = 0; r < 4; r++) { ps[i][r] = 0.f; pq[i][r] = 0.f; }
    #pragma unroll
    for (int i = 0; i < 2; i++) {
        #pragma unroll
        for (int j = 0; j < 2; j++) {
            const int col = n0w + j * 16 + lrow;
            const float bv = bf2f(opb[col]);
            #pragma unroll
            for (int r = 0; r < 4; r++) {
                const int row = i * 16 + quad * 4 + r;
                float v = accP[i][j][r] + bv + bf2f(cx[(size_t)(t0 + row) * 256 + col]);
                vP[i][j][r] = v;
                ps[i][r] += v;
                pq[i][r] += v * v;
            }
        }
    }
    #pragma unroll
    for (int i = 0; i < 2; i++)
        #pragma unroll
        for (int r = 0; r < 4; r++) {
            #pragma unroll
            for (int o = 8; o > 0; o >>= 1) {
                ps[i][r] += __shfl_xor(ps[i][r], o);
                pq[i][r] += __shfl_xor(pq[i][r], o);
            }
            if (lrow == 0) {
                const int row = i * 16 + quad * 4 + r;
                redS[wave * 32 + row] = ps[i][r];
                redQ[wave * 32 + row] = pq[i][r];
            }
        }
    __syncthreads();

    // LN1 -> y1bs (bf16) + y1f in registers
    float y1f[2][2][4];
    #pragma unroll
    for (int i = 0; i < 2; i++) {
        #pragma unroll
        for (int r = 0; r < 4; r++) {
            const int row = i * 16 + quad * 4 + r;
            float S = 0.f, Q = 0.f;
            #pragma unroll
            for (int w = 0; w < 8; w++) { S += redS[w * 32 + row]; Q += redQ[w * 32 + row]; }
            const float mean = S * (1.f / 256.f);
            const float var  = Q * (1.f / 256.f) - mean * mean;
            const float rs   = rsqrtf(var + 1e-5f);
            #pragma unroll
            for (int j = 0; j < 2; j++) {
                const int col = n0w + j * 16 + lrow;
                const float o2 = (vP[i][j][r] - mean) * rs * bf2f(ln1g[col]) + bf2f(ln1b[col]);
                y1f[i][j][r] = o2;
                y1bs[row * 264 + col] = f2bf(o2);
            }
        }
    }
    __syncthreads();

    // ---- fc1 (4 col-quarters) + fc2 partial-K accumulate; B prefetched ----
    f32x4 acc2[2][2];
    #pragma unroll
    for (int i = 0; i < 2; i++)
        #pragma unroll
        for (int j = 0; j < 2; j++)
            #pragma unroll
            for (int r = 0; r < 4; r++) acc2[i][j][r] = 0.f;

    for (int q = 0; q < 4; q++) {
        f32x4 a1[2][2];
        #pragma unroll
        for (int i = 0; i < 2; i++)
            #pragma unroll
            for (int j = 0; j < 2; j++)
                #pragma unroll
                for (int r = 0; r < 4; r++) a1[i][j][r] = 0.f;
        {
            const ushort* bp0 = f1w + (size_t)(q * 256 + n0w + lrow) * 256 + quad * 8;
            const ushort* bp1 = f1w + (size_t)(q * 256 + n0w + 16 + lrow) * 256 + quad * 8;
            bf16x8 bn0 = *(const bf16x8*)bp0;
            bf16x8 bn1 = *(const bf16x8*)bp1;
            for (int k0 = 0; k0 < 256; k0 += 32) {
                const bf16x8 bc0 = bn0, bc1 = bn1;
                if (k0 + 32 < 256) {
                    bn0 = *(const bf16x8*)(bp0 + k0 + 32);
                    bn1 = *(const bf16x8*)(bp1 + k0 + 32);
                }
                bf16x8 afr[2];
                #pragma unroll
                for (int i = 0; i < 2; i++)
                    afr[i] = *(const bf16x8*)&y1bs[(i * 16 + lrow) * 264 + k0 + quad * 8];
                #pragma unroll
                for (int i = 0; i < 2; i++) {
                    a1[i][0] = __builtin_amdgcn_mfma_f32_16x16x32_bf16(afr[i], bc0, a1[i][0], 0, 0, 0);
                    a1[i][1] = __builtin_amdgcn_mfma_f32_16x16x32_bf16(afr[i], bc1, a1[i][1], 0, 0, 0);
                }
            }
        }
        #pragma unroll
        for (int i = 0; i < 2; i++)
            #pragma unroll
            for (int j = 0; j < 2; j++) {
                const int qc = n0w + j * 16 + lrow;
                const float bv = bf2f(f1b[q * 256 + qc]);
                #pragma unroll
                for (int r = 0; r < 4; r++) {
                    const int row = i * 16 + quad * 4 + r;
                    f1q[row * 260 + qc] = f2bf(gelu_f(a1[i][j][r] + bv));
                }
            }
        __syncthreads();
        {
            const ushort* bp0 = f2w + (size_t)(n0w + lrow) * 1024 + q * 256 + quad * 8;
            const ushort* bp1 = f2w + (size_t)(n0w + 16 + lrow) * 1024 + q * 256 + quad * 8;
            bf16x8 bn0 = *(const bf16x8*)bp0;
            bf16x8 bn1 = *(const bf16x8*)bp1;
            for (int k0 = 0; k0 < 256; k0 += 32) {
                const bf16x8 bc0 = bn0, bc1 = bn1;
                if (k0 + 32 < 256) {
                    bn0 = *(const bf16x8*)(bp0 + k0 + 32);
                    bn1 = *(const bf16x8*)(bp1 + k0 + 32);
                }
                bf16x8 afr[2];
                #pragma unroll
                for (int i = 0; i < 2; i++)
                    afr[i] = *(const bf16x8*)&f1q[(i * 16 + lrow) * 260 + k0 + quad * 8];
                #pragma unroll
                for (int i = 0; i < 2; i++) {
                    acc2[i][0] = __builtin_amdgcn_mfma_f32_16x16x32_bf16(afr[i], bc0, acc2[i][0], 0, 0, 0);
                    acc2[i][1] = __builtin_amdgcn_mfma_f32_16x16x32_bf16(afr[i], bc1, acc2[i][1], 0, 0, 0);
                }
            }
        }
        __syncthreads();
    }

    // ---- fc2 epilogue: gelu + resid y1f, LN2, write d_out ----
    float v2[2][2][4];
    #pragma unroll
    for (int i = 0; i < 2; i++)
        #pragma unroll
        for (int r = 0; r < 4; r++) { ps[i][r] = 0.f; pq[i][r] = 0.f; }
    #pragma unroll
    for (int i = 0; i < 2; i++)
        #pragma unroll
        for (int j = 0; j < 2; j++) {
            const int col = n0w + j * 16 + lrow;
            const float bv = bf2f(f2b[col]);
            #pragma unroll
            for (int r = 0; r < 4; r++) {
                const float v = gelu_f(acc2[i][j][r] + bv) + y1f[i][j][r];
                v2[i][j][r] = v;
                ps[i][r] += v;
                pq[i][r] += v * v;
            }
        }
    #pragma unroll
    for (int i = 0; i < 2; i++)
        #pragma unroll
        for (int r = 0; r < 4; r++) {
            #pragma unroll
            for (int o = 8; o > 0; o >>= 1) {
                ps[i][r] += __shfl_xor(ps[i][r], o);
                pq[i][r] += __shfl_xor(pq[i][r], o);
            }
            if (lrow == 0) {
                const int row = i * 16 + quad * 4 + r;
                redS[wave * 32 + row] = ps[i][r];
                redQ[wave * 32 + row] = pq[i][r];
            }
        }
    __syncthreads();

    const bool fl = sniff_inline(sniffx);
    #pragma unroll
    for (int i = 0; i < 2; i++) {
        #pragma unroll
        for (int r = 0; r < 4; r++) {
            const int row = i * 16 + quad * 4 + r;
            float S = 0.f, Q = 0.f;
            #pragma unroll
            for (int w = 0; w < 8; w++) { S += redS[w * 32 + row]; Q += redQ[w * 32 + row]; }
            const float mean = S * (1.f / 256.f);
            const float var  = Q * (1.f / 256.f) - mean * mean;
            const float rs   = rsqrtf(var + 1e-5f);
            #pragma unroll
            for (int j = 0; j < 2; j++) {
                const int col = n0w + j * 16 + lrow;
                const size_t off = (size_t)(t0 + row) * 256 + col;
                const float o2 = (v2[i][j][r] - mean) * rs * bf2f(ln2g[col]) + bf2f(ln2b[col]);
                if (fl) ((ushort*)dout)[off] = f2bf(o2);
                else    ((float*)dout)[off]  = o2;
            }
        }
    }
}

// ---------------------------------------------------------------------------
extern "C" void kernel_launch(void* const* d_in, const int* in_sizes, int n_in,
                              void* d_out, int out_size, void* d_ws, size_t ws_size,
                              hipStream_t stream)
{
    char* ws = (char*)d_ws;
    ushort* canon = (ushort*)(ws + 256);

    static const int coff[20] = {
        0,        2097152,  2359296,  2360320,  2362368,
        2362880,  2387456,  2395648,  2396160,  2404352,
        2404864,  2535936,  2536192,  2536448,  2536704,
        2798848,  2799872,  3062016,  3062272,  3062528 };
    static const int ctot = 3062784;

    CanonArgs ca;
    for (int i = 0; i < 20; i++) { ca.src[i] = d_in[i]; ca.off[i] = coff[i]; }
    ca.total = ctot;

    const ushort* cx   = canon + coff[0];
    const ushort* cipw = canon + coff[1];
    const ushort* cipb = canon + coff[2];
    const ushort* ccw  = canon + coff[3];
    const ushort* ccb  = canon + coff[4];
    const ushort* cdtw = canon + coff[6];
    const ushort* cdtb = canon + coff[7];
    const ushort* calog= canon + coff[8];
    const ushort* cdssm= canon + coff[9];
    const ushort* copw = canon + coff[10];
    const ushort* copb = canon + coff[11];
    const ushort* cln1g= canon + coff[12];
    const ushort* cln1b= canon + coff[13];
    const ushort* cf1w = canon + coff[14];
    const ushort* cf1b = canon + coff[15];
    const ushort* cf2w = canon + coff[16];
    const ushort* cf2b = canon + coff[17];
    const ushort* cln2g= canon + coff[18];
    const ushort* cln2b= canon + coff[19];

    ushort* xpw_pad = (ushort*)(ws + 6291456);  // [64,512] bf16
    ushort* xz      = (ushort*)(ws + 8388608);  // [8192,1024] bf16, 16 MB
    float*  xdbl    = (float*)(ws + 25165824);  // [8192,64] f32, 2 MB
    float*  summ    = (float*)(ws + 27262976);  // [4,64,32,512] f32, 16 MB
    const ushort* sx = (const ushort*)d_in[0];

    // 1. canon + xpw padding
    canon_k<<<(ctot + 8192 + 255) / 256, 256, 0, stream>>>(ca, canon, xpw_pad, sx);
    // 2. in_proj: xz = x @ ipw^T + ipb
    gemm_bt<128, 128><<<dim3(64, 8), 256, 0, stream>>>(cx, cipw, cipb, xz, 1024, 256);
    // 3. conv + silu + xdbl + scan1 (fused, 32-token chunks)
    convscan1_k<<<dim3(64, 4), 512, 0, stream>>>(
        xz, ccw, ccb, xpw_pad, cdtw, cdtb, calog, xdbl, summ);
    // 4. combine (chunk-boundary states)
    combine_k<<<64, 512, 0, stream>>>(summ);
    // 5. tail: scan2 + out_proj + LN1 + fc1 + fc2 + LN2 -> d_out
    tail_k<<<dim3(64, 4), 512, 0, stream>>>(
        xz, ccw, ccb, xdbl, cdtw, cdtb, calog, summ, cdssm, cx,
        copw, copb, cln1g, cln1b, cf1w, cf1b, cf2w, cf2b, cln2g, cln2b,
        d_out, sx);
}